// Round 5
// baseline (105.569 us; speedup 1.0000x reference)
//
#include <hip/hip_runtime.h>
#include <hip/hip_bf16.h>

#define M_SAMP 4096
#define D_IN   100
#define HID    256
#define IN_DIM 101
#define NSQ    10000   // 100*100
#define NPAD   10112   // 79*128, padded rows of P

typedef __attribute__((ext_vector_type(8))) short short8;
typedef __attribute__((ext_vector_type(4))) float f32x4;

// async global->LDS, 16B/lane; LDS dst wave-uniform (HW adds lane*16)
__device__ __forceinline__ void gload_lds16(const void* g, void* l) {
    __builtin_amdgcn_global_load_lds(
        (const __attribute__((address_space(1))) void*)g,
        (__attribute__((address_space(3))) void*)l, 16, 0, 0);
}

// ---------------- kernel 1: W1T[j][h] = W1[h][j] ----------------
__global__ __launch_bounds__(256) void k_w1t(const float* __restrict__ W1,
                                             float* __restrict__ W1T) {
    int j = blockIdx.x;   // 0..100
    int h = threadIdx.x;  // 0..255
    W1T[j * HID + h] = W1[h * IN_DIM + j];
}

// ---------------- kernel 2: forward + grad (fp32), S2n (bf16) ----------------
__global__ __launch_bounds__(256) void k_fwd(
        const float* __restrict__ t, const float* __restrict__ X,
        const float* __restrict__ W1, const float* __restrict__ W1T,
        const float* __restrict__ b1, const float* __restrict__ W2,
        const float* __restrict__ b2,
        float* __restrict__ u_out, float* __restrict__ dux_out,
        float* __restrict__ dut_out, __hip_bfloat16* __restrict__ S2n) {
    const int SM = 8;
    __shared__ float s_in[SM][IN_DIM];
    __shared__ float c_sh[SM][HID];   // W2_h * cos(z)
    __shared__ float us_sh[SM][HID];  // W2_h * sin(z)

    int i0 = blockIdx.x * SM;
    int tid = threadIdx.x;

    for (int idx = tid; idx < SM * IN_DIM; idx += 256) {
        int i = idx / IN_DIM, j = idx % IN_DIM;
        s_in[i][j] = (j == 0) ? t[i0 + i] : X[(size_t)(i0 + i) * D_IN + (j - 1)];
    }
    __syncthreads();

    int h = tid;
    float z[SM];
    float bb = b1[h];
#pragma unroll
    for (int i = 0; i < SM; i++) z[i] = bb;
    for (int j = 0; j < IN_DIM; j++) {
        float w = W1T[j * HID + h];   // coalesced across lanes
#pragma unroll
        for (int i = 0; i < SM; i++) z[i] += w * s_in[i][j];
    }
    float w2 = W2[h];
#pragma unroll
    for (int i = 0; i < SM; i++) {
        float sz, cz;
        sincosf(z[i], &sz, &cz);
        c_sh[i][h] = w2 * cz;
        us_sh[i][h] = w2 * sz;
        S2n[(size_t)(i0 + i) * HID + h] = __float2bfloat16(-w2 * sz);
    }
    __syncthreads();

    for (int off = 128; off > 0; off >>= 1) {
        if (tid < off) {
#pragma unroll
            for (int i = 0; i < SM; i++) us_sh[i][tid] += us_sh[i][tid + off];
        }
        __syncthreads();
    }
    if (tid < SM) u_out[i0 + tid] = us_sh[tid][0] + b2[0];

    if (tid < IN_DIM) {
        float acc[SM];
#pragma unroll
        for (int i = 0; i < SM; i++) acc[i] = 0.f;
        for (int hh = 0; hh < HID; hh++) {
            float w = W1[hh * IN_DIM + tid];  // coalesced across lanes
#pragma unroll
            for (int i = 0; i < SM; i++) acc[i] += c_sh[i][hh] * w;
        }
        if (tid == 0) {
            for (int i = 0; i < SM; i++) dut_out[i0 + i] = acc[i];
        } else {
            for (int i = 0; i < SM; i++)
                dux_out[(size_t)(i0 + i) * D_IN + (tid - 1)] = acc[i];
        }
    }
}

// ---------------- kernel 3: P[n][h], vectorized 16B stores ----------------
__global__ __launch_bounds__(256) void k_pgen(const float* __restrict__ W1T,
                                              __hip_bfloat16* __restrict__ P) {
    int n0p = blockIdx.x * 16;
    int tid = threadIdx.x;
#pragma unroll
    for (int p = 0; p < 2; p++) {
        int n = n0p + (tid >> 5) + p * 8;
        int hb = (tid & 31) * 8;
        short8 v = {0, 0, 0, 0, 0, 0, 0, 0};
        if (n < NSQ) {
            int j = n / D_IN, k = n - j * D_IN;
            const float* wj = &W1T[(1 + j) * HID + hb];
            const float* wk = &W1T[(1 + k) * HID + hb];
#pragma unroll
            for (int e = 0; e < 8; e++) {
                __hip_bfloat16 hv = __float2bfloat16(wj[e] * wk[e]);
                v[e] = *reinterpret_cast<short*>(&hv);
            }
        }
        *(short8*)&P[(size_t)n * HID + hb] = v;
    }
}

// ---------------- kernel 4: H = S2n @ P^T (MFMA, transposed acc) ----------------
// Both-sides XOR swizzle (source pre-permuted, read same XOR), dbuf BK=64,
// operand-swapped MFMA so acc f32x4 = 4 consecutive n -> global_store_dwordx4.
#define BM 128
#define BN 128
#define BK 64
#define NK 4      // 256 / 64
#define NBLK 79   // NPAD / 128

__global__ __launch_bounds__(256) void k_gemm(
        const __hip_bfloat16* __restrict__ A,   // [4096][256] row-major
        const __hip_bfloat16* __restrict__ B,   // [NPAD][256] n-major (=B^T)
        float* __restrict__ C) {                // [4096][10000]
    __shared__ __hip_bfloat16 As[2][BM * BK];   // 2 x 16 KB
    __shared__ __hip_bfloat16 Bs[2][BM * BK];   // 2 x 16 KB

    int bid = blockIdx.x;
    int bm = bid / NBLK, bn = bid % NBLK;
    int m0 = bm * BM, n0 = bn * BN;
    int tid = threadIdx.x;
    int lane = tid & 63, wave = tid >> 6;
    int wm = wave >> 1, wn = wave & 1;   // 2x2 waves, 64x64 out each

    int srow8 = lane >> 3;               // r & 7
    int scol = ((lane & 7) ^ srow8) * 8; // pre-swizzled source col (bf16 elems)

    f32x4 acc[4][4];
#pragma unroll
    for (int i = 0; i < 4; i++)
#pragma unroll
        for (int j = 0; j < 4; j++) acc[i][j] = {0.f, 0.f, 0.f, 0.f};

    auto stage = [&](int buf, int kt) {
        int kc = kt * BK;
#pragma unroll
        for (int i = 0; i < 4; i++) {
            int rb = wave * 32 + i * 8;
            gload_lds16(A + (size_t)(m0 + rb + srow8) * HID + kc + scol,
                        &As[buf][rb * BK]);
            gload_lds16(B + (size_t)(n0 + rb + srow8) * HID + kc + scol,
                        &Bs[buf][rb * BK]);
        }
    };

    stage(0, 0);

    for (int kt = 0; kt < NK; kt++) {
        int cur = kt & 1;
        __syncthreads();                 // buf[cur] staged; readers of buf[cur^1] done
        if (kt + 1 < NK) stage(cur ^ 1, kt + 1);   // prefetch under compute

        const char* Ab = (const char*)As[cur];
        const char* Bb = (const char*)Bs[cur];
        int lo = lane & 15;
        int xr = (lane & 7) << 4;        // row-XOR term (r&7 == lane&7)
#pragma unroll
        for (int kk = 0; kk < 2; kk++) {
            int kbs = (kk * 64 + ((lane >> 4) << 4)) ^ xr;   // swizzled byte-in-row
            short8 af[4], bf4[4];
#pragma unroll
            for (int mi = 0; mi < 4; mi++)
                af[mi] = *(const short8*)(Ab + (wm * 64 + mi * 16 + lo) * 128 + kbs);
#pragma unroll
            for (int ni = 0; ni < 4; ni++)
                bf4[ni] = *(const short8*)(Bb + (wn * 64 + ni * 16 + lo) * 128 + kbs);
            // swapped operands: D = (A.B)^T per-fragment -> lane's f32x4 spans n
#pragma unroll
            for (int mi = 0; mi < 4; mi++)
#pragma unroll
                for (int ni = 0; ni < 4; ni++)
                    acc[mi][ni] = __builtin_amdgcn_mfma_f32_16x16x32_bf16(
                        bf4[ni], af[mi], acc[mi][ni], 0, 0, 0);
        }
    }

    // epilogue: m = lane&15 (fragment col), n = (lane>>4)*4 + reg (consecutive)
    int lo = lane & 15, hi4 = (lane >> 4) << 2;
#pragma unroll
    for (int mi = 0; mi < 4; mi++) {
        int mrow = m0 + wm * 64 + mi * 16 + lo;
#pragma unroll
        for (int ni = 0; ni < 4; ni++) {
            int ncol = n0 + wn * 64 + ni * 16 + hi4;
            if (ncol < NSQ)   // ncol%4==0, NSQ%4==0 -> covers all 4 elements
                *(f32x4*)&C[(size_t)mrow * NSQ + ncol] = acc[mi][ni];
        }
    }
}

extern "C" void kernel_launch(void* const* d_in, const int* in_sizes, int n_in,
                              void* d_out, int out_size, void* d_ws, size_t ws_size,
                              hipStream_t stream) {
    const float* t  = (const float*)d_in[0];
    const float* X  = (const float*)d_in[1];
    const float* W1 = (const float*)d_in[2];
    const float* b1 = (const float*)d_in[3];
    const float* W2 = (const float*)d_in[4];
    const float* b2 = (const float*)d_in[5];

    float* out = (float*)d_out;
    float* u_out = out;                                  // 4096
    float* dux   = out + M_SAMP;                         // 409600
    float* dut   = out + M_SAMP + (size_t)M_SAMP * D_IN; // 4096
    float* H     = dut + M_SAMP;                         // 40,960,000

    char* ws = (char*)d_ws;
    float* W1T          = (float*)ws;                               // 103,424 B
    __hip_bfloat16* S2n = (__hip_bfloat16*)(ws + 131072);           // 2 MB
    __hip_bfloat16* P   = (__hip_bfloat16*)(ws + 131072 + 2097152); // 5.18 MB

    k_w1t<<<IN_DIM, 256, 0, stream>>>(W1, W1T);
    k_fwd<<<M_SAMP / 8, 256, 0, stream>>>(t, X, W1, W1T, b1, W2, b2,
                                          u_out, dux, dut, S2n);
    k_pgen<<<NPAD / 16, 256, 0, stream>>>(W1T, P);
    k_gemm<<<(M_SAMP / BM) * NBLK, 256, 0, stream>>>(S2n, P, H);
}

// Round 6
// 102.527 us; speedup vs baseline: 1.0297x; 1.0297x over previous
//
#include <hip/hip_runtime.h>
#include <hip/hip_bf16.h>

#define M_SAMP 4096
#define D_IN   100
#define HID    256
#define IN_DIM 101
#define NSQ    10000   // 100*100
#define NPAD   10112   // 79*128, padded rows of P
#define SMF    4       // samples per fwd block
#define NFWD   (M_SAMP / SMF)   // 1024 fwd blocks

typedef __attribute__((ext_vector_type(8))) short short8;
typedef __attribute__((ext_vector_type(4))) float f32x4;

// async global->LDS, 16B/lane; LDS dst wave-uniform (HW adds lane*16)
__device__ __forceinline__ void gload_lds16(const void* g, void* l) {
    __builtin_amdgcn_global_load_lds(
        (const __attribute__((address_space(1))) void*)g,
        (__attribute__((address_space(3))) void*)l, 16, 0, 0);
}

// ======================= kernel 1: fused pre-pass ==========================
// blocks [0, NFWD)            : forward + grad + S2n (4 samples each)
// blocks [NFWD, NFWD+100)     : P rows j*100..j*100+99  (j = bid - NFWD)
// block  NFWD+100             : zero P pad rows 10000..10111
__global__ __launch_bounds__(256) void k_pre(
        const float* __restrict__ t, const float* __restrict__ X,
        const float* __restrict__ W1, const float* __restrict__ b1,
        const float* __restrict__ W2, const float* __restrict__ b2,
        float* __restrict__ u_out, float* __restrict__ dux,
        float* __restrict__ dut, __hip_bfloat16* __restrict__ S2n,
        __hip_bfloat16* __restrict__ P) {
    __shared__ __align__(16) char smem[51200];
    int tid = threadIdx.x, bid = blockIdx.x;

    if (bid < NFWD) {
        // ---------------- forward + grad ----------------
        float* s_in  = (float*)smem;                 // [4][101]
        float* c_sh  = (float*)(smem + 1664);        // [4][256]
        float* us_sh = (float*)(smem + 1664 + 4096); // [4][256]
        int i0 = bid * SMF;

        for (int idx = tid; idx < SMF * IN_DIM; idx += 256) {
            int i = idx / IN_DIM, j = idx % IN_DIM;
            s_in[i * IN_DIM + j] = (j == 0) ? t[i0 + i]
                                            : X[(size_t)(i0 + i) * D_IN + (j - 1)];
        }
        __syncthreads();

        int h = tid;
        float z[SMF];
        float bb = b1[h];
#pragma unroll
        for (int i = 0; i < SMF; i++) z[i] = bb;
        const float* wrow = W1 + (size_t)h * IN_DIM;   // own row, L1-sequential
        for (int j = 0; j < IN_DIM; j++) {
            float w = wrow[j];
#pragma unroll
            for (int i = 0; i < SMF; i++) z[i] += w * s_in[i * IN_DIM + j];
        }
        float w2 = W2[h];
#pragma unroll
        for (int i = 0; i < SMF; i++) {
            float sz, cz;
            sincosf(z[i], &sz, &cz);
            c_sh[i * HID + h]  = w2 * cz;
            us_sh[i * HID + h] = w2 * sz;
            S2n[(size_t)(i0 + i) * HID + h] = __float2bfloat16(-w2 * sz);
        }
        __syncthreads();

        for (int off = 128; off > 0; off >>= 1) {
            if (tid < off) {
#pragma unroll
                for (int i = 0; i < SMF; i++)
                    us_sh[i * HID + tid] += us_sh[i * HID + tid + off];
            }
            __syncthreads();
        }
        if (tid < SMF) u_out[i0 + tid] = us_sh[tid * HID] + b2[0];

        if (tid < IN_DIM) {
            float acc[SMF];
#pragma unroll
            for (int i = 0; i < SMF; i++) acc[i] = 0.f;
            // unroll-by-4 over h: 4 independent loads in flight per step
            for (int h0 = 0; h0 < HID; h0 += 4) {
                float w0 = W1[(size_t)(h0 + 0) * IN_DIM + tid];
                float w1 = W1[(size_t)(h0 + 1) * IN_DIM + tid];
                float w2_ = W1[(size_t)(h0 + 2) * IN_DIM + tid];
                float w3 = W1[(size_t)(h0 + 3) * IN_DIM + tid];
#pragma unroll
                for (int i = 0; i < SMF; i++)
                    acc[i] += c_sh[i * HID + h0] * w0 + c_sh[i * HID + h0 + 1] * w1
                            + c_sh[i * HID + h0 + 2] * w2_ + c_sh[i * HID + h0 + 3] * w3;
            }
            if (tid == 0) {
                for (int i = 0; i < SMF; i++) dut[i0 + i] = acc[i];
            } else {
                for (int i = 0; i < SMF; i++)
                    dux[(size_t)(i0 + i) * D_IN + (tid - 1)] = acc[i];
            }
        }
    } else if (bid < NFWD + D_IN) {
        // ---------------- P generation, one j per block ----------------
        int j = bid - NFWD;                       // 0..99
        __hip_bfloat16* Wb = (__hip_bfloat16*)smem;   // [100][256] bf16 = 50 KB
        const float* wrow = W1 + (size_t)tid * IN_DIM + 1;  // own x-row
        for (int k = 0; k < D_IN; k++)
            Wb[k * HID + tid] = __float2bfloat16(wrow[k]);  // lanes consecutive
        __syncthreads();

        int ksub = tid >> 5, h8 = (tid & 31) * 8;
        // hoist the j-row slice (constant per thread)
        float aj[8];
#pragma unroll
        for (int e = 0; e < 8; e++) aj[e] = __bfloat162float(Wb[j * HID + h8 + e]);

        for (int kk = 0; kk < 104; kk += 8) {
            int k = kk + ksub;
            if (k < D_IN) {
                short8 v;
#pragma unroll
                for (int e = 0; e < 8; e++) {
                    float b = __bfloat162float(Wb[k * HID + h8 + e]);
                    __hip_bfloat16 hv = __float2bfloat16(aj[e] * b);
                    v[e] = *reinterpret_cast<short*>(&hv);
                }
                *(short8*)&P[(size_t)(j * D_IN + k) * HID + h8] = v;
            }
        }
    } else {
        // ---------------- zero pad rows [10000, 10112) ----------------
        short8 zero = {0, 0, 0, 0, 0, 0, 0, 0};
        size_t base = (size_t)NSQ * HID;
        for (int idx = tid; idx < (NPAD - NSQ) * HID / 8; idx += 256)
            *(short8*)&P[base + (size_t)idx * 8] = zero;
    }
}

// ======================= kernel 2: H = S2n @ P^T (unchanged R5) ============
#define BM 128
#define BN 128
#define BK 64
#define NK 4      // 256 / 64
#define NBLK 79   // NPAD / 128

__global__ __launch_bounds__(256) void k_gemm(
        const __hip_bfloat16* __restrict__ A,   // [4096][256] row-major
        const __hip_bfloat16* __restrict__ B,   // [NPAD][256] n-major (=B^T)
        float* __restrict__ C) {                // [4096][10000]
    __shared__ __hip_bfloat16 As[2][BM * BK];   // 2 x 16 KB
    __shared__ __hip_bfloat16 Bs[2][BM * BK];   // 2 x 16 KB

    int bid = blockIdx.x;
    int bm = bid / NBLK, bn = bid % NBLK;
    int m0 = bm * BM, n0 = bn * BN;
    int tid = threadIdx.x;
    int lane = tid & 63, wave = tid >> 6;
    int wm = wave >> 1, wn = wave & 1;   // 2x2 waves, 64x64 out each

    int srow8 = lane >> 3;               // r & 7
    int scol = ((lane & 7) ^ srow8) * 8; // pre-swizzled source col (bf16 elems)

    f32x4 acc[4][4];
#pragma unroll
    for (int i = 0; i < 4; i++)
#pragma unroll
        for (int j = 0; j < 4; j++) acc[i][j] = {0.f, 0.f, 0.f, 0.f};

    auto stage = [&](int buf, int kt) {
        int kc = kt * BK;
#pragma unroll
        for (int i = 0; i < 4; i++) {
            int rb = wave * 32 + i * 8;
            gload_lds16(A + (size_t)(m0 + rb + srow8) * HID + kc + scol,
                        &As[buf][rb * BK]);
            gload_lds16(B + (size_t)(n0 + rb + srow8) * HID + kc + scol,
                        &Bs[buf][rb * BK]);
        }
    };

    stage(0, 0);

    for (int kt = 0; kt < NK; kt++) {
        int cur = kt & 1;
        __syncthreads();                 // buf[cur] staged; readers of buf[cur^1] done
        if (kt + 1 < NK) stage(cur ^ 1, kt + 1);   // prefetch under compute

        const char* Ab = (const char*)As[cur];
        const char* Bb = (const char*)Bs[cur];
        int lo = lane & 15;
        int xr = (lane & 7) << 4;        // row-XOR term (r&7 == lane&7)
#pragma unroll
        for (int kk = 0; kk < 2; kk++) {
            int kbs = (kk * 64 + ((lane >> 4) << 4)) ^ xr;   // swizzled byte-in-row
            short8 af[4], bf4[4];
#pragma unroll
            for (int mi = 0; mi < 4; mi++)
                af[mi] = *(const short8*)(Ab + (wm * 64 + mi * 16 + lo) * 128 + kbs);
#pragma unroll
            for (int ni = 0; ni < 4; ni++)
                bf4[ni] = *(const short8*)(Bb + (wn * 64 + ni * 16 + lo) * 128 + kbs);
            // swapped operands: D = (A.B)^T per-fragment -> lane's f32x4 spans n
#pragma unroll
            for (int mi = 0; mi < 4; mi++)
#pragma unroll
                for (int ni = 0; ni < 4; ni++)
                    acc[mi][ni] = __builtin_amdgcn_mfma_f32_16x16x32_bf16(
                        bf4[ni], af[mi], acc[mi][ni], 0, 0, 0);
        }
    }

    // epilogue: m = lane&15 (fragment col), n = (lane>>4)*4 + reg (consecutive)
    int lo = lane & 15, hi4 = (lane >> 4) << 2;
#pragma unroll
    for (int mi = 0; mi < 4; mi++) {
        int mrow = m0 + wm * 64 + mi * 16 + lo;
#pragma unroll
        for (int ni = 0; ni < 4; ni++) {
            int ncol = n0 + wn * 64 + ni * 16 + hi4;
            if (ncol < NSQ)   // ncol%4==0, NSQ%4==0 -> covers all 4 elements
                *(f32x4*)&C[(size_t)mrow * NSQ + ncol] = acc[mi][ni];
        }
    }
}

extern "C" void kernel_launch(void* const* d_in, const int* in_sizes, int n_in,
                              void* d_out, int out_size, void* d_ws, size_t ws_size,
                              hipStream_t stream) {
    const float* t  = (const float*)d_in[0];
    const float* X  = (const float*)d_in[1];
    const float* W1 = (const float*)d_in[2];
    const float* b1 = (const float*)d_in[3];
    const float* W2 = (const float*)d_in[4];
    const float* b2 = (const float*)d_in[5];

    float* out = (float*)d_out;
    float* u_out = out;                                  // 4096
    float* dux   = out + M_SAMP;                         // 409600
    float* dut   = out + M_SAMP + (size_t)M_SAMP * D_IN; // 4096
    float* H     = dut + M_SAMP;                         // 40,960,000

    char* ws = (char*)d_ws;
    __hip_bfloat16* S2n = (__hip_bfloat16*)ws;                // 2 MB
    __hip_bfloat16* P   = (__hip_bfloat16*)(ws + 2097152);    // 5.18 MB (padded)

    k_pre<<<NFWD + D_IN + 1, 256, 0, stream>>>(t, X, W1, b1, W2, b2,
                                               u_out, dux, dut, S2n, P);
    k_gemm<<<(M_SAMP / BM) * NBLK, 256, 0, stream>>>(S2n, P, H);
}